// Round 1
// baseline (498.459 us; speedup 1.0000x reference)
//
#include <hip/hip_runtime.h>
#include <hip/hip_bf16.h>
#include <stdint.h>

// OldQuantLinear: y = x @ (scales.T * unpack4(qweight) - zeros.T) + bias
// x: [M=8192, K=4096] f32, qweight: [K/8, N=4096] i32 (8 nibbles along K, LSB first),
// scales/zeros: [N] f32, bias: [N] f32, out: [M, N] f32.
// bf16 MFMA GEMM with fused dequant. Tile 128x128x64, 4 waves (2x2), each wave
// computes 64x64 via 4x4 fragments of mfma_f32_16x16x32_bf16.

#define TILE_M 128
#define TILE_N 128
#define TILE_K 64

using f32x4  = __attribute__((ext_vector_type(4))) float;
using bf16x8 = __attribute__((ext_vector_type(8))) __bf16;
using u16x8  = __attribute__((ext_vector_type(8))) unsigned short;

__device__ __forceinline__ unsigned short f2bf(float f) {
    union { float f; uint32_t u; } v; v.f = f;
    uint32_t u = v.u + 0x7FFFu + ((v.u >> 16) & 1u);   // RNE, finite inputs
    return (unsigned short)(u >> 16);
}

__global__ __launch_bounds__(256) void qgemm_kernel(
    const float* __restrict__ x, const int* __restrict__ qw,
    const float* __restrict__ scales, const float* __restrict__ zeros,
    const float* __restrict__ bias, float* __restrict__ out,
    int M, int N, int K)
{
    // K-contiguous rows, 16B granules, XOR-swizzled granule slot (T2-style)
    __shared__ __align__(16) unsigned short Alds[TILE_M * TILE_K]; // [m][k]
    __shared__ __align__(16) unsigned short Blds[TILE_N * TILE_K]; // [n][k]

    const int tid  = threadIdx.x;
    const int lane = tid & 63;
    const int wave = tid >> 6;
    const int wm = wave >> 1;      // 0..1  (M half)
    const int wn = wave & 1;       // 0..1  (N half)
    const int lrow = lane & 15;    // fragment row/col index
    const int lkb  = lane >> 4;    // fragment k-block (0..3)

    const int nTilesN = N / TILE_N;
    const int bm = blockIdx.x / nTilesN;
    const int bn = blockIdx.x % nTilesN;
    const int brow = bm * TILE_M;
    const int bcol = bn * TILE_N;

    // per-thread dequant column (fixed for whole kernel)
    const int bc  = tid & 127;     // col within tile
    const int qr0 = tid >> 7;      // 0..1
    const float s = scales[bcol + bc];
    const float z = zeros[bcol + bc];

    f32x4 acc[4][4];
    #pragma unroll
    for (int i = 0; i < 4; ++i)
        #pragma unroll
        for (int j = 0; j < 4; ++j)
            acc[i][j] = (f32x4){0.f, 0.f, 0.f, 0.f};

    for (int kt = 0; kt < K; kt += TILE_K) {
        // ---- stage A: fp32 -> bf16, 8-elem granules, one ds_write_b128 each ----
        #pragma unroll
        for (int i = 0; i < 4; ++i) {
            int g  = tid + i * 256;        // 0..1023 granules
            int r  = g >> 3;               // 0..127
            int kb = g & 7;                // 0..7
            const float* p = x + (size_t)(brow + r) * K + kt + kb * 8;
            f32x4 f0 = *(const f32x4*)p;
            f32x4 f1 = *(const f32x4*)(p + 4);
            u16x8 v;
            v[0] = f2bf(f0[0]); v[1] = f2bf(f0[1]); v[2] = f2bf(f0[2]); v[3] = f2bf(f0[3]);
            v[4] = f2bf(f1[0]); v[5] = f2bf(f1[1]); v[6] = f2bf(f1[2]); v[7] = f2bf(f1[3]);
            int slot = kb ^ (r & 7);
            *(u16x8*)&Alds[r * TILE_K + slot * 8] = v;
        }
        // ---- stage B: int4 dequant -> bf16, one int32 -> one ds_write_b128 ----
        #pragma unroll
        for (int i = 0; i < 4; ++i) {
            int qr = qr0 + i * 2;          // 0..7 (k granule within tile)
            uint32_t w = (uint32_t)qw[(size_t)(kt / 8 + qr) * N + bcol + bc];
            u16x8 v;
            #pragma unroll
            for (int j = 0; j < 8; ++j) {
                float q = (float)((w >> (4 * j)) & 15u);
                v[j] = f2bf(s * q - z);
            }
            int slot = qr ^ (bc & 7);
            *(u16x8*)&Blds[bc * TILE_K + slot * 8] = v;
        }
        __syncthreads();

        // ---- compute: 2 k-steps x 16 MFMA ----
        #pragma unroll
        for (int ks = 0; ks < 2; ++ks) {
            bf16x8 af[4], bfr[4];
            #pragma unroll
            for (int mf = 0; mf < 4; ++mf) {
                int m = wm * 64 + mf * 16 + lrow;
                int kb = ks * 4 + lkb;
                int slot = kb ^ (m & 7);
                af[mf] = __builtin_bit_cast(bf16x8, *(const u16x8*)&Alds[m * TILE_K + slot * 8]);
            }
            #pragma unroll
            for (int nf = 0; nf < 4; ++nf) {
                int n = wn * 64 + nf * 16 + lrow;
                int kb = ks * 4 + lkb;
                int slot = kb ^ (n & 7);
                bfr[nf] = __builtin_bit_cast(bf16x8, *(const u16x8*)&Blds[n * TILE_K + slot * 8]);
            }
            #pragma unroll
            for (int mf = 0; mf < 4; ++mf)
                #pragma unroll
                for (int nf = 0; nf < 4; ++nf)
                    acc[mf][nf] = __builtin_amdgcn_mfma_f32_16x16x32_bf16(
                        af[mf], bfr[nf], acc[mf][nf], 0, 0, 0);
        }
        __syncthreads();
    }

    // ---- epilogue: D[row = (lane>>4)*4 + i][col = lane&15], + bias ----
    #pragma unroll
    for (int nf = 0; nf < 4; ++nf) {
        int col = bcol + wn * 64 + nf * 16 + lrow;
        float bv = bias[col];
        #pragma unroll
        for (int mf = 0; mf < 4; ++mf) {
            int row = brow + wm * 64 + mf * 16 + lkb * 4;
            #pragma unroll
            for (int i = 0; i < 4; ++i)
                out[(size_t)(row + i) * N + col] = acc[mf][nf][i] + bv;
        }
    }
}

extern "C" void kernel_launch(void* const* d_in, const int* in_sizes, int n_in,
                              void* d_out, int out_size, void* d_ws, size_t ws_size,
                              hipStream_t stream) {
    const float* x      = (const float*)d_in[0];
    const int*   qw     = (const int*)d_in[1];
    const float* scales = (const float*)d_in[2];
    const float* zeros  = (const float*)d_in[3];
    const float* bias   = (const float*)d_in[4];
    float* out = (float*)d_out;

    const int N = in_sizes[4];                 // OUT = bias size
    const int K = (int)(((long long)in_sizes[1] * 8) / N);  // IN from packed qweight
    const int M = in_sizes[0] / K;

    dim3 grid((M / TILE_M) * (N / TILE_N));
    qgemm_kernel<<<grid, 256, 0, stream>>>(x, qw, scales, zeros, bias, out, M, N, K);
}

// Round 2
// 429.636 us; speedup vs baseline: 1.1602x; 1.1602x over previous
//
#include <hip/hip_runtime.h>
#include <hip/hip_bf16.h>
#include <stdint.h>

// OldQuantLinear: y = x @ (scales.T * unpack4(qweight) - zeros.T) + bias
// x: [M=8192, K=4096] f32, qweight: [K/8, N=4096] i32 (8 nibbles along K, LSB first),
// scales/zeros: [N] f32, bias: [N] f32, out: [M, N] f32.
// bf16 MFMA GEMM with fused dequant. Tile 128x128x64, 4 waves (2x2), each wave
// computes 64x64 via 4x4 fragments of mfma_f32_16x16x32_bf16.
// R2: cheap staging VALU — native bf16 casts (cvt_pk) for A, byte-plane nibble
// extract (cvt_f32_ubyte) + single fma for B dequant.

#define TILE_M 128
#define TILE_N 128
#define TILE_K 64

using f32x4  = __attribute__((ext_vector_type(4))) float;
using bf16x8 = __attribute__((ext_vector_type(8))) __bf16;

__global__ __launch_bounds__(256) void qgemm_kernel(
    const float* __restrict__ x, const int* __restrict__ qw,
    const float* __restrict__ scales, const float* __restrict__ zeros,
    const float* __restrict__ bias, float* __restrict__ out,
    int M, int N, int K)
{
    // K-contiguous rows, 16B granules, XOR-swizzled granule slot (T2-style)
    __shared__ __align__(16) __bf16 Alds[TILE_M * TILE_K]; // [m][k]
    __shared__ __align__(16) __bf16 Blds[TILE_N * TILE_K]; // [n][k]

    const int tid  = threadIdx.x;
    const int lane = tid & 63;
    const int wave = tid >> 6;
    const int wm = wave >> 1;      // 0..1  (M half)
    const int wn = wave & 1;       // 0..1  (N half)
    const int lrow = lane & 15;    // fragment row/col index
    const int lkb  = lane >> 4;    // fragment k-block (0..3)

    const int nTilesN = N / TILE_N;
    const int bm = blockIdx.x / nTilesN;
    const int bn = blockIdx.x % nTilesN;
    const int brow = bm * TILE_M;
    const int bcol = bn * TILE_N;

    // per-thread dequant column (fixed for whole kernel)
    const int bc  = tid & 127;     // col within tile
    const int qr0 = tid >> 7;      // 0..1
    const float s  = scales[bcol + bc];
    const float nz = -zeros[bcol + bc];

    f32x4 acc[4][4];
    #pragma unroll
    for (int i = 0; i < 4; ++i)
        #pragma unroll
        for (int j = 0; j < 4; ++j)
            acc[i][j] = (f32x4){0.f, 0.f, 0.f, 0.f};

    for (int kt = 0; kt < K; kt += TILE_K) {
        // ---- stage A: fp32 -> bf16 (compiler emits v_cvt_pk_bf16_f32) ----
        #pragma unroll
        for (int i = 0; i < 4; ++i) {
            int g  = tid + i * 256;        // 0..1023 granules
            int r  = g >> 3;               // 0..127
            int kb = g & 7;                // 0..7
            const float* p = x + (size_t)(brow + r) * K + kt + kb * 8;
            f32x4 f0 = *(const f32x4*)p;
            f32x4 f1 = *(const f32x4*)(p + 4);
            bf16x8 v;
            v[0] = (__bf16)f0[0]; v[1] = (__bf16)f0[1];
            v[2] = (__bf16)f0[2]; v[3] = (__bf16)f0[3];
            v[4] = (__bf16)f1[0]; v[5] = (__bf16)f1[1];
            v[6] = (__bf16)f1[2]; v[7] = (__bf16)f1[3];
            int slot = kb ^ (r & 7);
            *(bf16x8*)&Alds[r * TILE_K + slot * 8] = v;
        }
        // ---- stage B: int4 dequant via byte planes (v_cvt_f32_ubyte + fma) ----
        #pragma unroll
        for (int i = 0; i < 4; ++i) {
            int qr = qr0 + i * 2;          // 0..7 (k granule within tile)
            uint32_t w = (uint32_t)qw[(size_t)(kt / 8 + qr) * N + bcol + bc];
            uint32_t lo = w & 0x0F0F0F0Fu;          // nibbles 0,2,4,6 as bytes
            uint32_t hi = (w >> 4) & 0x0F0F0F0Fu;   // nibbles 1,3,5,7 as bytes
            bf16x8 v;
            v[0] = (__bf16)fmaf(s, (float)(lo & 0xFFu),         nz);
            v[1] = (__bf16)fmaf(s, (float)(hi & 0xFFu),         nz);
            v[2] = (__bf16)fmaf(s, (float)((lo >> 8)  & 0xFFu), nz);
            v[3] = (__bf16)fmaf(s, (float)((hi >> 8)  & 0xFFu), nz);
            v[4] = (__bf16)fmaf(s, (float)((lo >> 16) & 0xFFu), nz);
            v[5] = (__bf16)fmaf(s, (float)((hi >> 16) & 0xFFu), nz);
            v[6] = (__bf16)fmaf(s, (float)(lo >> 24),           nz);
            v[7] = (__bf16)fmaf(s, (float)(hi >> 24),           nz);
            int slot = qr ^ (bc & 7);
            *(bf16x8*)&Blds[bc * TILE_K + slot * 8] = v;
        }
        __syncthreads();

        // ---- compute: 2 k-steps x 16 MFMA ----
        #pragma unroll
        for (int ks = 0; ks < 2; ++ks) {
            // row&7 == lrow&7 for both A and B fragments (wm*64, mf*16 are 0 mod 8)
            const int slot = (ks * 4 + lkb) ^ (lrow & 7);
            const int abase = (wm * 64 + lrow) * TILE_K + slot * 8;
            const int bbase = (wn * 64 + lrow) * TILE_K + slot * 8;
            bf16x8 af[4], bfr[4];
            #pragma unroll
            for (int mf = 0; mf < 4; ++mf)
                af[mf] = *(const bf16x8*)&Alds[abase + mf * 16 * TILE_K];
            #pragma unroll
            for (int nf = 0; nf < 4; ++nf)
                bfr[nf] = *(const bf16x8*)&Blds[bbase + nf * 16 * TILE_K];
            #pragma unroll
            for (int mf = 0; mf < 4; ++mf)
                #pragma unroll
                for (int nf = 0; nf < 4; ++nf)
                    acc[mf][nf] = __builtin_amdgcn_mfma_f32_16x16x32_bf16(
                        af[mf], bfr[nf], acc[mf][nf], 0, 0, 0);
        }
        __syncthreads();
    }

    // ---- epilogue: D[row = (lane>>4)*4 + i][col = lane&15], + bias ----
    #pragma unroll
    for (int nf = 0; nf < 4; ++nf) {
        int col = bcol + wn * 64 + nf * 16 + lrow;
        float bv = bias[col];
        #pragma unroll
        for (int mf = 0; mf < 4; ++mf) {
            int row = brow + wm * 64 + mf * 16 + lkb * 4;
            #pragma unroll
            for (int i = 0; i < 4; ++i)
                out[(size_t)(row + i) * N + col] = acc[mf][nf][i] + bv;
        }
    }
}

extern "C" void kernel_launch(void* const* d_in, const int* in_sizes, int n_in,
                              void* d_out, int out_size, void* d_ws, size_t ws_size,
                              hipStream_t stream) {
    const float* x      = (const float*)d_in[0];
    const int*   qw     = (const int*)d_in[1];
    const float* scales = (const float*)d_in[2];
    const float* zeros  = (const float*)d_in[3];
    const float* bias   = (const float*)d_in[4];
    float* out = (float*)d_out;

    const int N = in_sizes[4];                 // OUT = bias size
    const int K = (int)(((long long)in_sizes[1] * 8) / N);  // IN from packed qweight
    const int M = in_sizes[0] / K;

    dim3 grid((M / TILE_M) * (N / TILE_N));
    qgemm_kernel<<<grid, 256, 0, stream>>>(x, qw, scales, zeros, bias, out, M, N, K);
}

// Round 3
// 379.965 us; speedup vs baseline: 1.3119x; 1.1307x over previous
//
#include <hip/hip_runtime.h>
#include <hip/hip_bf16.h>
#include <stdint.h>

// OldQuantLinear: y = x @ (scales.T * unpack4(qweight) - zeros.T) + bias
// R3: three-kernel plan.
//   1) cvt_x:    x f32 [M,K]      -> xb bf16 [M,K]        (d_ws)
//   2) dequant:  qw i32 [K/8,N]   -> Wt bf16 [N,K] (B^T)  (d_ws, LDS transpose)
//   3) qgemm:    pure bf16 MFMA GEMM, m97 structure: 128x128x64 tile, 4 waves,
//      global_load_lds width=16, pre-swizzled global source + linear LDS dest,
//      swizzled ds_read_b128 fragments.
// Fallback: fused kernel (R2) if ws_size < 96 MB.

#define TILE_M 128
#define TILE_N 128
#define TILE_K 64

using f32x4  = __attribute__((ext_vector_type(4))) float;
using bf16x8 = __attribute__((ext_vector_type(8))) __bf16;

typedef const uint32_t __attribute__((address_space(1)))* gas_ptr;
typedef uint32_t __attribute__((address_space(3)))* las_ptr;

__device__ __forceinline__ void gload_lds16(const void* g, void* l) {
    __builtin_amdgcn_global_load_lds((gas_ptr)g, (las_ptr)l, 16, 0, 0);
}

// ---------------- pre-pass 1: x f32 -> bf16 ----------------
__global__ __launch_bounds__(256) void cvt_x_kernel(
    const float* __restrict__ x, __bf16* __restrict__ xb, size_t n8)
{
    size_t i = (size_t)blockIdx.x * 256 + threadIdx.x;
    if (i >= n8) return;
    const f32x4* p = (const f32x4*)(x + i * 8);
    f32x4 a = p[0], b = p[1];
    bf16x8 v;
    v[0] = (__bf16)a[0]; v[1] = (__bf16)a[1]; v[2] = (__bf16)a[2]; v[3] = (__bf16)a[3];
    v[4] = (__bf16)b[0]; v[5] = (__bf16)b[1]; v[6] = (__bf16)b[2]; v[7] = (__bf16)b[3];
    *(bf16x8*)(xb + i * 8) = v;
}

// ---------------- pre-pass 2: qweight -> Wt [N][K] bf16 ----------------
// tile: 32 kg-rows x 64 n-cols, transposed through slot-swizzled LDS.
__global__ __launch_bounds__(256) void dequant_w_kernel(
    const int* __restrict__ qw, const float* __restrict__ scales,
    const float* __restrict__ zeros, __bf16* __restrict__ Wt, int N, int K)
{
    __shared__ __align__(16) __bf16 T[64 * 32 * 8];   // [n_l][slot] 16B granules, 32KB
    const int tid = threadIdx.x;
    const int nTilesN = N >> 6;
    const int kg0 = (blockIdx.x / nTilesN) << 5;
    const int n0  = (blockIdx.x % nTilesN) << 6;

    #pragma unroll
    for (int it = 0; it < 8; ++it) {
        int idx  = it * 256 + tid;
        int kg_l = idx >> 6, n_l = idx & 63;
        int n = n0 + n_l;
        float s = scales[n], nz = -zeros[n];
        uint32_t w  = (uint32_t)qw[(size_t)(kg0 + kg_l) * N + n];
        uint32_t lo = w & 0x0F0F0F0Fu;
        uint32_t hi = (w >> 4) & 0x0F0F0F0Fu;
        bf16x8 v;
        v[0] = (__bf16)fmaf(s, (float)(lo & 0xFFu),         nz);
        v[1] = (__bf16)fmaf(s, (float)(hi & 0xFFu),         nz);
        v[2] = (__bf16)fmaf(s, (float)((lo >> 8)  & 0xFFu), nz);
        v[3] = (__bf16)fmaf(s, (float)((hi >> 8)  & 0xFFu), nz);
        v[4] = (__bf16)fmaf(s, (float)((lo >> 16) & 0xFFu), nz);
        v[5] = (__bf16)fmaf(s, (float)((hi >> 16) & 0xFFu), nz);
        v[6] = (__bf16)fmaf(s, (float)(lo >> 24),           nz);
        v[7] = (__bf16)fmaf(s, (float)(hi >> 24),           nz);
        int slot = kg_l ^ (n_l & 7);
        *(bf16x8*)&T[(size_t)(n_l * 32 + slot) * 8] = v;
    }
    __syncthreads();
    #pragma unroll
    for (int it = 0; it < 8; ++it) {
        int idx  = it * 256 + tid;
        int n_l  = idx >> 5, kg_l = idx & 31;
        bf16x8 v = *(const bf16x8*)&T[(size_t)(n_l * 32 + (kg_l ^ (n_l & 7))) * 8];
        *(bf16x8*)&Wt[(size_t)(n0 + n_l) * K + (size_t)(kg0 + kg_l) * 8] = v;
    }
}

// ---------------- main GEMM: bf16, m97 structure ----------------
__global__ __launch_bounds__(256) void qgemm_pre_kernel(
    const __bf16* __restrict__ A, const __bf16* __restrict__ Bt,
    const float* __restrict__ bias, float* __restrict__ out,
    int M, int N, int K)
{
    __shared__ __align__(16) __bf16 Alds[TILE_M * TILE_K];
    __shared__ __align__(16) __bf16 Blds[TILE_N * TILE_K];

    const int tid  = threadIdx.x;
    const int l    = tid & 63;
    const int w    = tid >> 6;
    const int wm   = w >> 1, wn = w & 1;
    const int lrow = l & 15, lkb = l >> 4;

    const int nTilesN = N / TILE_N;
    const int brow = (blockIdx.x / nTilesN) * TILE_M;
    const int bcol = (blockIdx.x % nTilesN) * TILE_N;

    // staging: wave w instr i writes LDS granules [(w*4+i)*64 + l]; lane l holds
    // row r = (w*4+i)*8 + (l>>3), slot = l&7, content kb = slot ^ (r&7) = (l&7)^(l>>3)
    const int kb = (l & 7) ^ (l >> 3);
    const int r0 = w * 32 + (l >> 3);
    const __bf16* aS = A  + (size_t)(brow + r0) * K + kb * 8;
    const __bf16* bS = Bt + (size_t)(bcol + r0) * K + kb * 8;
    __bf16* aD = &Alds[(size_t)w * 4 * 512];
    __bf16* bD = &Blds[(size_t)w * 4 * 512];

    f32x4 acc[4][4];
    #pragma unroll
    for (int i = 0; i < 4; ++i)
        #pragma unroll
        for (int j = 0; j < 4; ++j)
            acc[i][j] = (f32x4){0.f, 0.f, 0.f, 0.f};

    for (int kt = 0; kt < K; kt += TILE_K) {
        #pragma unroll
        for (int i = 0; i < 4; ++i) {
            gload_lds16(aS + (size_t)i * 8 * K + kt, aD + i * 512);
            gload_lds16(bS + (size_t)i * 8 * K + kt, bD + i * 512);
        }
        __syncthreads();   // compiler emits vmcnt(0) before barrier

        #pragma unroll
        for (int ks = 0; ks < 2; ++ks) {
            const int slot  = (ks * 4 + lkb) ^ (lrow & 7);
            const int abase = (wm * 64 + lrow) * TILE_K + slot * 8;
            const int bbase = (wn * 64 + lrow) * TILE_K + slot * 8;
            bf16x8 af[4], bfr[4];
            #pragma unroll
            for (int mf = 0; mf < 4; ++mf)
                af[mf] = *(const bf16x8*)&Alds[abase + mf * 16 * TILE_K];
            #pragma unroll
            for (int nf = 0; nf < 4; ++nf)
                bfr[nf] = *(const bf16x8*)&Blds[bbase + nf * 16 * TILE_K];
            #pragma unroll
            for (int mf = 0; mf < 4; ++mf)
                #pragma unroll
                for (int nf = 0; nf < 4; ++nf)
                    acc[mf][nf] = __builtin_amdgcn_mfma_f32_16x16x32_bf16(
                        af[mf], bfr[nf], acc[mf][nf], 0, 0, 0);
        }
        __syncthreads();
    }

    #pragma unroll
    for (int nf = 0; nf < 4; ++nf) {
        int col = bcol + wn * 64 + nf * 16 + lrow;
        float bv = bias[col];
        #pragma unroll
        for (int mf = 0; mf < 4; ++mf) {
            int row = brow + wm * 64 + mf * 16 + lkb * 4;
            #pragma unroll
            for (int i = 0; i < 4; ++i)
                out[(size_t)(row + i) * N + col] = acc[mf][nf][i] + bv;
        }
    }
}

// ---------------- fallback: R2 fused kernel ----------------
__global__ __launch_bounds__(256) void qgemm_fused_kernel(
    const float* __restrict__ x, const int* __restrict__ qw,
    const float* __restrict__ scales, const float* __restrict__ zeros,
    const float* __restrict__ bias, float* __restrict__ out,
    int M, int N, int K)
{
    __shared__ __align__(16) __bf16 Alds[TILE_M * TILE_K];
    __shared__ __align__(16) __bf16 Blds[TILE_N * TILE_K];

    const int tid  = threadIdx.x;
    const int lane = tid & 63;
    const int wave = tid >> 6;
    const int wm = wave >> 1, wn = wave & 1;
    const int lrow = lane & 15, lkb = lane >> 4;

    const int nTilesN = N / TILE_N;
    const int brow = (blockIdx.x / nTilesN) * TILE_M;
    const int bcol = (blockIdx.x % nTilesN) * TILE_N;

    const int bc  = tid & 127;
    const int qr0 = tid >> 7;
    const float s  = scales[bcol + bc];
    const float nz = -zeros[bcol + bc];

    f32x4 acc[4][4];
    #pragma unroll
    for (int i = 0; i < 4; ++i)
        #pragma unroll
        for (int j = 0; j < 4; ++j)
            acc[i][j] = (f32x4){0.f, 0.f, 0.f, 0.f};

    for (int kt = 0; kt < K; kt += TILE_K) {
        #pragma unroll
        for (int i = 0; i < 4; ++i) {
            int g  = tid + i * 256;
            int r  = g >> 3;
            int kbg = g & 7;
            const float* p = x + (size_t)(brow + r) * K + kt + kbg * 8;
            f32x4 f0 = *(const f32x4*)p;
            f32x4 f1 = *(const f32x4*)(p + 4);
            bf16x8 v;
            v[0] = (__bf16)f0[0]; v[1] = (__bf16)f0[1];
            v[2] = (__bf16)f0[2]; v[3] = (__bf16)f0[3];
            v[4] = (__bf16)f1[0]; v[5] = (__bf16)f1[1];
            v[6] = (__bf16)f1[2]; v[7] = (__bf16)f1[3];
            int slot = kbg ^ (r & 7);
            *(bf16x8*)&Alds[r * TILE_K + slot * 8] = v;
        }
        #pragma unroll
        for (int i = 0; i < 4; ++i) {
            int qr = qr0 + i * 2;
            uint32_t wv = (uint32_t)qw[(size_t)(kt / 8 + qr) * N + bcol + bc];
            uint32_t lo = wv & 0x0F0F0F0Fu;
            uint32_t hi = (wv >> 4) & 0x0F0F0F0Fu;
            bf16x8 v;
            v[0] = (__bf16)fmaf(s, (float)(lo & 0xFFu),         nz);
            v[1] = (__bf16)fmaf(s, (float)(hi & 0xFFu),         nz);
            v[2] = (__bf16)fmaf(s, (float)((lo >> 8)  & 0xFFu), nz);
            v[3] = (__bf16)fmaf(s, (float)((hi >> 8)  & 0xFFu), nz);
            v[4] = (__bf16)fmaf(s, (float)((lo >> 16) & 0xFFu), nz);
            v[5] = (__bf16)fmaf(s, (float)((hi >> 16) & 0xFFu), nz);
            v[6] = (__bf16)fmaf(s, (float)(lo >> 24),           nz);
            v[7] = (__bf16)fmaf(s, (float)(hi >> 24),           nz);
            int slot = qr ^ (bc & 7);
            *(bf16x8*)&Blds[bc * TILE_K + slot * 8] = v;
        }
        __syncthreads();

        #pragma unroll
        for (int ks = 0; ks < 2; ++ks) {
            const int slot = (ks * 4 + lkb) ^ (lrow & 7);
            const int abase = (wm * 64 + lrow) * TILE_K + slot * 8;
            const int bbase = (wn * 64 + lrow) * TILE_K + slot * 8;
            bf16x8 af[4], bfr[4];
            #pragma unroll
            for (int mf = 0; mf < 4; ++mf)
                af[mf] = *(const bf16x8*)&Alds[abase + mf * 16 * TILE_K];
            #pragma unroll
            for (int nf = 0; nf < 4; ++nf)
                bfr[nf] = *(const bf16x8*)&Blds[bbase + nf * 16 * TILE_K];
            #pragma unroll
            for (int mf = 0; mf < 4; ++mf)
                #pragma unroll
                for (int nf = 0; nf < 4; ++nf)
                    acc[mf][nf] = __builtin_amdgcn_mfma_f32_16x16x32_bf16(
                        af[mf], bfr[nf], acc[mf][nf], 0, 0, 0);
        }
        __syncthreads();
    }

    #pragma unroll
    for (int nf = 0; nf < 4; ++nf) {
        int col = bcol + wn * 64 + nf * 16 + lrow;
        float bv = bias[col];
        #pragma unroll
        for (int mf = 0; mf < 4; ++mf) {
            int row = brow + wm * 64 + mf * 16 + lkb * 4;
            #pragma unroll
            for (int i = 0; i < 4; ++i)
                out[(size_t)(row + i) * N + col] = acc[mf][nf][i] + bv;
        }
    }
}

extern "C" void kernel_launch(void* const* d_in, const int* in_sizes, int n_in,
                              void* d_out, int out_size, void* d_ws, size_t ws_size,
                              hipStream_t stream) {
    const float* x      = (const float*)d_in[0];
    const int*   qw     = (const int*)d_in[1];
    const float* scales = (const float*)d_in[2];
    const float* zeros  = (const float*)d_in[3];
    const float* bias   = (const float*)d_in[4];
    float* out = (float*)d_out;

    const int N = in_sizes[4];                              // OUT
    const int K = (int)(((long long)in_sizes[1] * 8) / N);  // IN
    const int M = in_sizes[0] / K;

    const size_t xb_elems = (size_t)M * K;
    const size_t wt_elems = (size_t)N * K;
    const size_t need = (xb_elems + wt_elems) * sizeof(__bf16);

    if (ws_size >= need) {
        __bf16* xb = (__bf16*)d_ws;
        __bf16* Wt = xb + xb_elems;

        size_t n8 = xb_elems / 8;
        cvt_x_kernel<<<dim3((unsigned)((n8 + 255) / 256)), 256, 0, stream>>>(x, xb, n8);

        dim3 dq_grid((unsigned)(((K / 8) / 32) * (N / 64)));
        dequant_w_kernel<<<dq_grid, 256, 0, stream>>>(qw, scales, zeros, Wt, N, K);

        dim3 grid((M / TILE_M) * (N / TILE_N));
        qgemm_pre_kernel<<<grid, 256, 0, stream>>>(xb, Wt, bias, out, M, N, K);
    } else {
        dim3 grid((M / TILE_M) * (N / TILE_N));
        qgemm_fused_kernel<<<grid, 256, 0, stream>>>(x, qw, scales, zeros, bias, out, M, N, K);
    }
}

// Round 4
// 325.405 us; speedup vs baseline: 1.5318x; 1.1677x over previous
//
#include <hip/hip_runtime.h>
#include <hip/hip_bf16.h>
#include <stdint.h>

// OldQuantLinear: y = x @ (scales.T * unpack4(qweight) - zeros.T) + bias
// R4: pre-dequant (R3) + deep-pipelined 256x256 bf16 MFMA GEMM:
//   BK=32, 4-buffer LDS ring (128 KiB), 2 phases/K-tile {8|4 ds_read_b128,
//   2 global_load_lds, bar, lgkm0, setprio1, 16 MFMA, setprio0, bar},
//   counted vmcnt(4) once per K-tile (T4), stage lead = 3 K-tiles,
//   XCD-aware block swizzle (T1), setprio (T5).

#define BM 256
#define BN 256
#define BK 32
#define NBUF 4

using f32x4  = __attribute__((ext_vector_type(4))) float;
using bf16x8 = __attribute__((ext_vector_type(8))) __bf16;

typedef const uint32_t __attribute__((address_space(1)))* gas_ptr;
typedef uint32_t __attribute__((address_space(3)))* las_ptr;

__device__ __forceinline__ void gl16(const __bf16* g, __bf16* l) {
    __builtin_amdgcn_global_load_lds((gas_ptr)g, (las_ptr)l, 16, 0, 0);
}

// ---------------- pre-pass 1: x f32 -> bf16 ----------------
__global__ __launch_bounds__(256) void cvt_x_kernel(
    const float* __restrict__ x, __bf16* __restrict__ xb, size_t n8)
{
    size_t i = (size_t)blockIdx.x * 256 + threadIdx.x;
    if (i >= n8) return;
    const f32x4* p = (const f32x4*)(x + i * 8);
    f32x4 a = p[0], b = p[1];
    bf16x8 v;
    v[0] = (__bf16)a[0]; v[1] = (__bf16)a[1]; v[2] = (__bf16)a[2]; v[3] = (__bf16)a[3];
    v[4] = (__bf16)b[0]; v[5] = (__bf16)b[1]; v[6] = (__bf16)b[2]; v[7] = (__bf16)b[3];
    *(bf16x8*)(xb + i * 8) = v;
}

// ---------------- pre-pass 2: qweight -> Wt [N][K] bf16 ----------------
__global__ __launch_bounds__(256) void dequant_w_kernel(
    const int* __restrict__ qw, const float* __restrict__ scales,
    const float* __restrict__ zeros, __bf16* __restrict__ Wt, int N, int K)
{
    __shared__ __align__(16) __bf16 T[64 * 32 * 8];
    const int tid = threadIdx.x;
    const int nTilesN = N >> 6;
    const int kg0 = (blockIdx.x / nTilesN) << 5;
    const int n0  = (blockIdx.x % nTilesN) << 6;

    #pragma unroll
    for (int it = 0; it < 8; ++it) {
        int idx  = it * 256 + tid;
        int kg_l = idx >> 6, n_l = idx & 63;
        int n = n0 + n_l;
        float s = scales[n], nz = -zeros[n];
        uint32_t w  = (uint32_t)qw[(size_t)(kg0 + kg_l) * N + n];
        uint32_t lo = w & 0x0F0F0F0Fu;
        uint32_t hi = (w >> 4) & 0x0F0F0F0Fu;
        bf16x8 v;
        v[0] = (__bf16)fmaf(s, (float)(lo & 0xFFu),         nz);
        v[1] = (__bf16)fmaf(s, (float)(hi & 0xFFu),         nz);
        v[2] = (__bf16)fmaf(s, (float)((lo >> 8)  & 0xFFu), nz);
        v[3] = (__bf16)fmaf(s, (float)((hi >> 8)  & 0xFFu), nz);
        v[4] = (__bf16)fmaf(s, (float)((lo >> 16) & 0xFFu), nz);
        v[5] = (__bf16)fmaf(s, (float)((hi >> 16) & 0xFFu), nz);
        v[6] = (__bf16)fmaf(s, (float)(lo >> 24),           nz);
        v[7] = (__bf16)fmaf(s, (float)(hi >> 24),           nz);
        int slot = kg_l ^ (n_l & 7);
        *(bf16x8*)&T[(size_t)(n_l * 32 + slot) * 8] = v;
    }
    __syncthreads();
    #pragma unroll
    for (int it = 0; it < 8; ++it) {
        int idx  = it * 256 + tid;
        int n_l  = idx >> 5, kg_l = idx & 31;
        bf16x8 v = *(const bf16x8*)&T[(size_t)(n_l * 32 + (kg_l ^ (n_l & 7))) * 8];
        *(bf16x8*)&Wt[(size_t)(n0 + n_l) * K + (size_t)(kg0 + kg_l) * 8] = v;
    }
}

// ---------------- main GEMM: 256x256, 8 waves, 4-deep ring ----------------
__global__ __launch_bounds__(512) void qgemm8_kernel(
    const __bf16* __restrict__ A, const __bf16* __restrict__ Bt,
    const float* __restrict__ bias, float* __restrict__ out,
    int M, int N, int K)
{
    __shared__ __align__(16) __bf16 Alds[NBUF * BM * BK];  // 64 KiB
    __shared__ __align__(16) __bf16 Blds[NBUF * BN * BK];  // 64 KiB

    const int tid = threadIdx.x;
    const int l   = tid & 63;
    const int w   = tid >> 6;
    const int wm  = w >> 2;        // 0..1 (M half, 128 rows)
    const int wn  = w & 3;         // 0..3 (N quarter, 64 cols)
    const int lr  = l & 15;
    const int lg  = l >> 4;        // 0..3

    // T1: bijective XCD swizzle (nwg % 8 == 0 guaranteed by launcher shapes)
    int bid = (int)blockIdx.x;
    const int nwg = (int)gridDim.x;
    if ((nwg & 7) == 0) bid = (bid & 7) * (nwg >> 3) + (bid >> 3);

    const int nTilesN = N / BN;
    const int brow = (bid / nTilesN) * BM;
    const int bcol = (bid % nTilesN) * BN;

    // staging geometry: granule gi = w*128 + j*64 + l; row = gi>>2, g = gi&3
    const int srow = w * 32 + (l >> 2);
    const int sg   = l & 3;
    const __bf16* aS0 = A  + (size_t)(brow + srow) * K + sg * 8;
    const __bf16* aS1 = aS0 + (size_t)16 * K;
    const __bf16* bS0 = Bt + (size_t)(bcol + srow) * K + sg * 8;
    const __bf16* bS1 = bS0 + (size_t)16 * K;
    __bf16* aD0 = &Alds[(w * 128) * 8];        // wave-uniform; HW adds lane*16B
    __bf16* aD1 = &Alds[(w * 128 + 64) * 8];
    __bf16* bD0 = &Blds[(w * 128) * 8];
    __bf16* bD1 = &Blds[(w * 128 + 64) * 8];

    #define STAGE_A(tt) { const size_t ko = (size_t)(tt) * BK;            \
        const int sb = ((tt) & 3) * (BM * BK);                            \
        gl16(aS0 + ko, aD0 + sb); gl16(aS1 + ko, aD1 + sb); }
    #define STAGE_B(tt) { const size_t ko = (size_t)(tt) * BK;            \
        const int sb = ((tt) & 3) * (BN * BK);                            \
        gl16(bS0 + ko, bD0 + sb); gl16(bS1 + ko, bD1 + sb); }

    f32x4 acc[8][4];
    #pragma unroll
    for (int i = 0; i < 8; ++i)
        #pragma unroll
        for (int j = 0; j < 4; ++j)
            acc[i][j] = (f32x4){0.f, 0.f, 0.f, 0.f};

    const int NT = K / BK;

    // prologue: stage tiles 0,1,2 (12 loads/thread); wait own tile-0 (vmcnt 8); join
    STAGE_A(0); STAGE_B(0);
    STAGE_A(1); STAGE_B(1);
    STAGE_A(2); STAGE_B(2);
    asm volatile("s_waitcnt vmcnt(8)" ::: "memory");
    __builtin_amdgcn_s_barrier();

    for (int t = 0; t < NT; ++t) {
        const int bo = (t & 3) * (BM * BK);
        const int abase = bo + (wm * 128 + lr) * BK + lg * 8;
        const int bbase = bo + (wn * 64  + lr) * BK + lg * 8;
        const bool pre = (t + 3 < NT);
        bf16x8 af[4], bfr[4];

        // ---- phase 1: m-frags 0-3 x n-frags 0-3 ----
        #pragma unroll
        for (int mf = 0; mf < 4; ++mf)
            af[mf] = *(const bf16x8*)&Alds[abase + mf * 16 * BK];
        #pragma unroll
        for (int nf = 0; nf < 4; ++nf)
            bfr[nf] = *(const bf16x8*)&Blds[bbase + nf * 16 * BK];
        if (pre) STAGE_A(t + 3);
        __builtin_amdgcn_s_barrier();
        asm volatile("s_waitcnt lgkmcnt(0)" ::: "memory");
        __builtin_amdgcn_s_setprio(1);
        #pragma unroll
        for (int mf = 0; mf < 4; ++mf)
            #pragma unroll
            for (int nf = 0; nf < 4; ++nf)
                acc[mf][nf] = __builtin_amdgcn_mfma_f32_16x16x32_bf16(
                    af[mf], bfr[nf], acc[mf][nf], 0, 0, 0);
        __builtin_amdgcn_s_setprio(0);
        __builtin_amdgcn_s_barrier();

        // ---- phase 2: m-frags 4-7 (reuse B frags) ----
        #pragma unroll
        for (int mf = 0; mf < 4; ++mf)
            af[mf] = *(const bf16x8*)&Alds[abase + (mf + 4) * 16 * BK];
        if (pre) STAGE_B(t + 3);
        __builtin_amdgcn_s_barrier();
        asm volatile("s_waitcnt lgkmcnt(0)" ::: "memory");
        __builtin_amdgcn_s_setprio(1);
        #pragma unroll
        for (int mf = 0; mf < 4; ++mf)
            #pragma unroll
            for (int nf = 0; nf < 4; ++nf)
                acc[mf + 4][nf] = __builtin_amdgcn_mfma_f32_16x16x32_bf16(
                    af[mf], bfr[nf], acc[mf + 4][nf], 0, 0, 0);
        __builtin_amdgcn_s_setprio(0);
        // counted vmcnt: retire t+2's 4 loads, keep this tile's 4 in flight
        if (pre) { asm volatile("s_waitcnt vmcnt(4)" ::: "memory"); }
        else     { asm volatile("s_waitcnt vmcnt(0)" ::: "memory"); }
        __builtin_amdgcn_s_barrier();
    }

    // ---- epilogue ----
    #pragma unroll
    for (int nf = 0; nf < 4; ++nf) {
        int col = bcol + wn * 64 + nf * 16 + lr;
        float bv = bias[col];
        #pragma unroll
        for (int mf = 0; mf < 8; ++mf) {
            int row = brow + wm * 128 + mf * 16 + lg * 4;
            #pragma unroll
            for (int i = 0; i < 4; ++i)
                out[(size_t)(row + i) * N + col] = acc[mf][nf][i] + bv;
        }
    }
    #undef STAGE_A
    #undef STAGE_B
}

// ---------------- fallback: fused kernel (R2) ----------------
#define FT_M 128
#define FT_N 128
#define FT_K 64
__global__ __launch_bounds__(256) void qgemm_fused_kernel(
    const float* __restrict__ x, const int* __restrict__ qw,
    const float* __restrict__ scales, const float* __restrict__ zeros,
    const float* __restrict__ bias, float* __restrict__ out,
    int M, int N, int K)
{
    __shared__ __align__(16) __bf16 Alds[FT_M * FT_K];
    __shared__ __align__(16) __bf16 Blds[FT_N * FT_K];

    const int tid  = threadIdx.x;
    const int lane = tid & 63;
    const int wave = tid >> 6;
    const int wm = wave >> 1, wn = wave & 1;
    const int lrow = lane & 15, lkb = lane >> 4;

    const int nTilesN = N / FT_N;
    const int brow = (blockIdx.x / nTilesN) * FT_M;
    const int bcol = (blockIdx.x % nTilesN) * FT_N;

    const int bc  = tid & 127;
    const int qr0 = tid >> 7;
    const float s  = scales[bcol + bc];
    const float nz = -zeros[bcol + bc];

    f32x4 acc[4][4];
    #pragma unroll
    for (int i = 0; i < 4; ++i)
        #pragma unroll
        for (int j = 0; j < 4; ++j)
            acc[i][j] = (f32x4){0.f, 0.f, 0.f, 0.f};

    for (int kt = 0; kt < K; kt += FT_K) {
        #pragma unroll
        for (int i = 0; i < 4; ++i) {
            int g  = tid + i * 256;
            int r  = g >> 3;
            int kbg = g & 7;
            const float* p = x + (size_t)(brow + r) * K + kt + kbg * 8;
            f32x4 f0 = *(const f32x4*)p;
            f32x4 f1 = *(const f32x4*)(p + 4);
            bf16x8 v;
            v[0] = (__bf16)f0[0]; v[1] = (__bf16)f0[1];
            v[2] = (__bf16)f0[2]; v[3] = (__bf16)f0[3];
            v[4] = (__bf16)f1[0]; v[5] = (__bf16)f1[1];
            v[6] = (__bf16)f1[2]; v[7] = (__bf16)f1[3];
            int slot = kbg ^ (r & 7);
            *(bf16x8*)&Alds[r * FT_K + slot * 8] = v;
        }
        #pragma unroll
        for (int i = 0; i < 4; ++i) {
            int qr = qr0 + i * 2;
            uint32_t wv = (uint32_t)qw[(size_t)(kt / 8 + qr) * N + bcol + bc];
            uint32_t lo = wv & 0x0F0F0F0Fu;
            uint32_t hi = (wv >> 4) & 0x0F0F0F0Fu;
            bf16x8 v;
            v[0] = (__bf16)fmaf(s, (float)(lo & 0xFFu),         nz);
            v[1] = (__bf16)fmaf(s, (float)(hi & 0xFFu),         nz);
            v[2] = (__bf16)fmaf(s, (float)((lo >> 8)  & 0xFFu), nz);
            v[3] = (__bf16)fmaf(s, (float)((hi >> 8)  & 0xFFu), nz);
            v[4] = (__bf16)fmaf(s, (float)((lo >> 16) & 0xFFu), nz);
            v[5] = (__bf16)fmaf(s, (float)((hi >> 16) & 0xFFu), nz);
            v[6] = (__bf16)fmaf(s, (float)(lo >> 24),           nz);
            v[7] = (__bf16)fmaf(s, (float)(hi >> 24),           nz);
            int slot = qr ^ (bc & 7);
            *(bf16x8*)&Blds[bc * FT_K + slot * 8] = v;
        }
        __syncthreads();

        #pragma unroll
        for (int ks = 0; ks < 2; ++ks) {
            const int slot = (ks * 4 + lkb) ^ (lrow & 7);
            const int abase = (wm * 64 + lrow) * FT_K + slot * 8;
            const int bbase = (wn * 64 + lrow) * FT_K + slot * 8;
            bf16x8 af[4], bfr[4];
            #pragma unroll
            for (int mf = 0; mf < 4; ++mf)
                af[mf] = *(const bf16x8*)&Alds[abase + mf * 16 * FT_K];
            #pragma unroll
            for (int nf = 0; nf < 4; ++nf)
                bfr[nf] = *(const bf16x8*)&Blds[bbase + nf * 16 * FT_K];
            #pragma unroll
            for (int mf = 0; mf < 4; ++mf)
                #pragma unroll
                for (int nf = 0; nf < 4; ++nf)
                    acc[mf][nf] = __builtin_amdgcn_mfma_f32_16x16x32_bf16(
                        af[mf], bfr[nf], acc[mf][nf], 0, 0, 0);
        }
        __syncthreads();
    }

    #pragma unroll
    for (int nf = 0; nf < 4; ++nf) {
        int col = bcol + wn * 64 + nf * 16 + lrow;
        float bv = bias[col];
        #pragma unroll
        for (int mf = 0; mf < 4; ++mf) {
            int row = brow + wm * 64 + mf * 16 + lkb * 4;
            #pragma unroll
            for (int i = 0; i < 4; ++i)
                out[(size_t)(row + i) * N + col] = acc[mf][nf][i] + bv;
        }
    }
}

extern "C" void kernel_launch(void* const* d_in, const int* in_sizes, int n_in,
                              void* d_out, int out_size, void* d_ws, size_t ws_size,
                              hipStream_t stream) {
    const float* x      = (const float*)d_in[0];
    const int*   qw     = (const int*)d_in[1];
    const float* scales = (const float*)d_in[2];
    const float* zeros  = (const float*)d_in[3];
    const float* bias   = (const float*)d_in[4];
    float* out = (float*)d_out;

    const int N = in_sizes[4];                              // OUT
    const int K = (int)(((long long)in_sizes[1] * 8) / N);  // IN
    const int M = in_sizes[0] / K;

    const size_t xb_elems = (size_t)M * K;
    const size_t wt_elems = (size_t)N * K;
    const size_t need = (xb_elems + wt_elems) * sizeof(__bf16);

    const bool shapes_ok = (M % BM == 0) && (N % BN == 0) && (K % BK == 0) &&
                           (K / BK >= 4) && (N % 64 == 0) && (K % 256 == 0);

    if (ws_size >= need && shapes_ok) {
        __bf16* xb = (__bf16*)d_ws;
        __bf16* Wt = xb + xb_elems;

        size_t n8 = xb_elems / 8;
        cvt_x_kernel<<<dim3((unsigned)((n8 + 255) / 256)), 256, 0, stream>>>(x, xb, n8);

        dim3 dq_grid((unsigned)(((K / 8) / 32) * (N / 64)));
        dequant_w_kernel<<<dq_grid, 256, 0, stream>>>(qw, scales, zeros, Wt, N, K);

        dim3 grid((M / BM) * (N / BN));
        qgemm8_kernel<<<grid, 512, 0, stream>>>(xb, Wt, bias, out, M, N, K);
    } else {
        dim3 grid((M / FT_M) * (N / FT_N));
        qgemm_fused_kernel<<<grid, 256, 0, stream>>>(x, qw, scales, zeros, bias, out, M, N, K);
    }
}

// Round 6
// 320.412 us; speedup vs baseline: 1.5557x; 1.0156x over previous
//
#include <hip/hip_runtime.h>
#include <hip/hip_bf16.h>
#include <stdint.h>

// OldQuantLinear: y = x @ (scales.T * unpack4(qweight) - zeros.T) + bias
// R6: R4 pipeline (pre-dequant + 256x256 BK=32 4-deep-ring bf16 GEMM) with the
// BK=32 bank-conflict swizzle, staging geometry CORRECTED (R5 bug: LDS dest
// granule base was w*256 instead of w*128 -> waves 4-7 overwrote ring bufs
// and read rows 256..511 of a 256-row tile).
//   LDS granule gi = w*128 + j*64 + l; row = gi>>2 = w*32+j*16+(l>>2);
//   slot_pos = l&3; granule holds k-granule kb = slot_pos ^ ((row>>1)&3)
//     = (l&3) ^ ((l>>3)&3)  [source-side swizzle, linear LDS dest — rule 21]
//   read: rslot = lg ^ ((lr>>1)&3)  (16-lane quarter covers all 8 bank-slots)
//   steady-state vmcnt(8) (retire only t+1's 4 loads; t+2,t+3 stay in flight)

#define BM 256
#define BN 256
#define BK 32
#define NBUF 4

using f32x4  = __attribute__((ext_vector_type(4))) float;
using bf16x8 = __attribute__((ext_vector_type(8))) __bf16;

typedef const uint32_t __attribute__((address_space(1)))* gas_ptr;
typedef uint32_t __attribute__((address_space(3)))* las_ptr;

__device__ __forceinline__ void gl16(const __bf16* g, __bf16* l) {
    __builtin_amdgcn_global_load_lds((gas_ptr)g, (las_ptr)l, 16, 0, 0);
}

// ---------------- pre-pass 1: x f32 -> bf16 ----------------
__global__ __launch_bounds__(256) void cvt_x_kernel(
    const float* __restrict__ x, __bf16* __restrict__ xb, size_t n8)
{
    size_t i = (size_t)blockIdx.x * 256 + threadIdx.x;
    if (i >= n8) return;
    const f32x4* p = (const f32x4*)(x + i * 8);
    f32x4 a = p[0], b = p[1];
    bf16x8 v;
    v[0] = (__bf16)a[0]; v[1] = (__bf16)a[1]; v[2] = (__bf16)a[2]; v[3] = (__bf16)a[3];
    v[4] = (__bf16)b[0]; v[5] = (__bf16)b[1]; v[6] = (__bf16)b[2]; v[7] = (__bf16)b[3];
    *(bf16x8*)(xb + i * 8) = v;
}

// ---------------- pre-pass 2: qweight -> Wt [N][K] bf16 ----------------
__global__ __launch_bounds__(256) void dequant_w_kernel(
    const int* __restrict__ qw, const float* __restrict__ scales,
    const float* __restrict__ zeros, __bf16* __restrict__ Wt, int N, int K)
{
    __shared__ __align__(16) __bf16 T[64 * 32 * 8];
    const int tid = threadIdx.x;
    const int nTilesN = N >> 6;
    const int kg0 = (blockIdx.x / nTilesN) << 5;
    const int n0  = (blockIdx.x % nTilesN) << 6;

    #pragma unroll
    for (int it = 0; it < 8; ++it) {
        int idx  = it * 256 + tid;
        int kg_l = idx >> 6, n_l = idx & 63;
        int n = n0 + n_l;
        float s = scales[n], nz = -zeros[n];
        uint32_t w  = (uint32_t)qw[(size_t)(kg0 + kg_l) * N + n];
        uint32_t lo = w & 0x0F0F0F0Fu;
        uint32_t hi = (w >> 4) & 0x0F0F0F0Fu;
        bf16x8 v;
        v[0] = (__bf16)fmaf(s, (float)(lo & 0xFFu),         nz);
        v[1] = (__bf16)fmaf(s, (float)(hi & 0xFFu),         nz);
        v[2] = (__bf16)fmaf(s, (float)((lo >> 8)  & 0xFFu), nz);
        v[3] = (__bf16)fmaf(s, (float)((hi >> 8)  & 0xFFu), nz);
        v[4] = (__bf16)fmaf(s, (float)((lo >> 16) & 0xFFu), nz);
        v[5] = (__bf16)fmaf(s, (float)((hi >> 16) & 0xFFu), nz);
        v[6] = (__bf16)fmaf(s, (float)(lo >> 24),           nz);
        v[7] = (__bf16)fmaf(s, (float)(hi >> 24),           nz);
        int slot = kg_l ^ (n_l & 7);
        *(bf16x8*)&T[(size_t)(n_l * 32 + slot) * 8] = v;
    }
    __syncthreads();
    #pragma unroll
    for (int it = 0; it < 8; ++it) {
        int idx  = it * 256 + tid;
        int n_l  = idx >> 5, kg_l = idx & 31;
        bf16x8 v = *(const bf16x8*)&T[(size_t)(n_l * 32 + (kg_l ^ (n_l & 7))) * 8];
        *(bf16x8*)&Wt[(size_t)(n0 + n_l) * K + (size_t)(kg0 + kg_l) * 8] = v;
    }
}

// ---------------- main GEMM: 256x256, 8 waves, 4-deep ring, swizzled LDS ----
__global__ __launch_bounds__(512) void qgemm8_kernel(
    const __bf16* __restrict__ A, const __bf16* __restrict__ Bt,
    const float* __restrict__ bias, float* __restrict__ out,
    int M, int N, int K)
{
    __shared__ __align__(16) __bf16 Alds[NBUF * BM * BK];  // 64 KiB
    __shared__ __align__(16) __bf16 Blds[NBUF * BN * BK];  // 64 KiB

    const int tid = threadIdx.x;
    const int l   = tid & 63;
    const int w   = tid >> 6;
    const int wm  = w >> 2;        // 0..1 (M half, 128 rows)
    const int wn  = w & 3;         // 0..3 (N quarter, 64 cols)
    const int lr  = l & 15;
    const int lg  = l >> 4;        // 0..3

    // T1: bijective XCD swizzle (nwg % 8 == 0 for our shapes)
    int bid = (int)blockIdx.x;
    const int nwg = (int)gridDim.x;
    if ((nwg & 7) == 0) bid = (bid & 7) * (nwg >> 3) + (bid >> 3);

    const int nTilesN = N / BN;
    const int brow = (bid / nTilesN) * BM;
    const int bcol = (bid % nTilesN) * BN;

    // staging (R4 geometry + source-side k-granule swizzle):
    //   gi = w*128 + j*64 + l ; row = w*32 + j*16 + (l>>2) ; slot_pos = l&3
    //   kb = (l&3) ^ ((l>>3)&3)
    const int skb  = (l & 3) ^ ((l >> 3) & 3);
    const int srow = w * 32 + (l >> 2);
    const __bf16* aS0 = A  + (size_t)(brow + srow) * K + skb * 8;
    const __bf16* aS1 = aS0 + (size_t)16 * K;            // j=1: +16 rows
    const __bf16* bS0 = Bt + (size_t)(bcol + srow) * K + skb * 8;
    const __bf16* bS1 = bS0 + (size_t)16 * K;
    __bf16* aD0 = &Alds[(w * 128) * 8];       // wave-uniform; HW adds lane*16B
    __bf16* aD1 = &Alds[(w * 128 + 64) * 8];
    __bf16* bD0 = &Blds[(w * 128) * 8];
    __bf16* bD1 = &Blds[(w * 128 + 64) * 8];

    #define STAGE_A(tt) { const size_t ko = (size_t)(tt) * BK;            \
        const int sb = ((tt) & 3) * (BM * BK);                            \
        gl16(aS0 + ko, aD0 + sb); gl16(aS1 + ko, aD1 + sb); }
    #define STAGE_B(tt) { const size_t ko = (size_t)(tt) * BK;            \
        const int sb = ((tt) & 3) * (BN * BK);                            \
        gl16(bS0 + ko, bD0 + sb); gl16(bS1 + ko, bD1 + sb); }

    f32x4 acc[8][4];
    #pragma unroll
    for (int i = 0; i < 8; ++i)
        #pragma unroll
        for (int j = 0; j < 4; ++j)
            acc[i][j] = (f32x4){0.f, 0.f, 0.f, 0.f};

    const int NT = K / BK;

    // read-side swizzled slot: row = {wm*128|wn*64} + mf*16 + lr; all terms but
    // lr are multiples of 16 -> (row>>1)&3 == (lr>>1)&3 (mf/nf-invariant).
    const int rslot = lg ^ ((lr >> 1) & 3);

    // prologue: stage tiles 0,1,2 (12 loads/thread); wait tile 0 (keep 8 in flight)
    STAGE_A(0); STAGE_B(0);
    STAGE_A(1); STAGE_B(1);
    STAGE_A(2); STAGE_B(2);
    asm volatile("s_waitcnt vmcnt(8)" ::: "memory");
    __builtin_amdgcn_s_barrier();

    for (int t = 0; t < NT; ++t) {
        const int bo = (t & 3) * (BM * BK);
        const int abase = bo + (wm * 128 + lr) * BK + rslot * 8;
        const int bbase = bo + (wn * 64  + lr) * BK + rslot * 8;
        const bool pre = (t + 3 < NT);
        bf16x8 af[4], bfr[4];

        // ---- phase 1: m-frags 0-3 x n-frags 0-3 ----
        #pragma unroll
        for (int mf = 0; mf < 4; ++mf)
            af[mf] = *(const bf16x8*)&Alds[abase + mf * 16 * BK];
        #pragma unroll
        for (int nf = 0; nf < 4; ++nf)
            bfr[nf] = *(const bf16x8*)&Blds[bbase + nf * 16 * BK];
        if (pre) STAGE_A(t + 3);
        __builtin_amdgcn_s_barrier();
        asm volatile("s_waitcnt lgkmcnt(0)" ::: "memory");
        __builtin_amdgcn_s_setprio(1);
        #pragma unroll
        for (int mf = 0; mf < 4; ++mf)
            #pragma unroll
            for (int nf = 0; nf < 4; ++nf)
                acc[mf][nf] = __builtin_amdgcn_mfma_f32_16x16x32_bf16(
                    af[mf], bfr[nf], acc[mf][nf], 0, 0, 0);
        __builtin_amdgcn_s_setprio(0);
        __builtin_amdgcn_s_barrier();

        // ---- phase 2: m-frags 4-7 (reuse B frags) ----
        #pragma unroll
        for (int mf = 0; mf < 4; ++mf)
            af[mf] = *(const bf16x8*)&Alds[abase + (mf + 4) * 16 * BK];
        if (pre) STAGE_B(t + 3);
        __builtin_amdgcn_s_barrier();
        asm volatile("s_waitcnt lgkmcnt(0)" ::: "memory");
        __builtin_amdgcn_s_setprio(1);
        #pragma unroll
        for (int mf = 0; mf < 4; ++mf)
            #pragma unroll
            for (int nf = 0; nf < 4; ++nf)
                acc[mf + 4][nf] = __builtin_amdgcn_mfma_f32_16x16x32_bf16(
                    af[mf], bfr[nf], acc[mf + 4][nf], 0, 0, 0);
        __builtin_amdgcn_s_setprio(0);
        // counted vmcnt: retire exactly tile t+1's 4 loads
        //   steady (t+3 staged): in-flight 12 -> vmcnt(8)
        //   t == NT-3: in-flight 8 -> vmcnt(4);  t >= NT-2: vmcnt(0)
        if (pre)              { asm volatile("s_waitcnt vmcnt(8)" ::: "memory"); }
        else if (t + 2 < NT)  { asm volatile("s_waitcnt vmcnt(4)" ::: "memory"); }
        else                  { asm volatile("s_waitcnt vmcnt(0)" ::: "memory"); }
        __builtin_amdgcn_s_barrier();
    }

    // ---- epilogue ----
    #pragma unroll
    for (int nf = 0; nf < 4; ++nf) {
        int col = bcol + wn * 64 + nf * 16 + lr;
        float bv = bias[col];
        #pragma unroll
        for (int mf = 0; mf < 8; ++mf) {
            int row = brow + wm * 128 + mf * 16 + lg * 4;
            #pragma unroll
            for (int i = 0; i < 4; ++i)
                out[(size_t)(row + i) * N + col] = acc[mf][nf][i] + bv;
        }
    }
    #undef STAGE_A
    #undef STAGE_B
}

// ---------------- fallback: fused kernel (R2) ----------------
#define FT_M 128
#define FT_N 128
#define FT_K 64
__global__ __launch_bounds__(256) void qgemm_fused_kernel(
    const float* __restrict__ x, const int* __restrict__ qw,
    const float* __restrict__ scales, const float* __restrict__ zeros,
    const float* __restrict__ bias, float* __restrict__ out,
    int M, int N, int K)
{
    __shared__ __align__(16) __bf16 Alds[FT_M * FT_K];
    __shared__ __align__(16) __bf16 Blds[FT_N * FT_K];

    const int tid  = threadIdx.x;
    const int lane = tid & 63;
    const int wave = tid >> 6;
    const int wm = wave >> 1, wn = wave & 1;
    const int lrow = lane & 15, lkb = lane >> 4;

    const int nTilesN = N / FT_N;
    const int brow = (blockIdx.x / nTilesN) * FT_M;
    const int bcol = (blockIdx.x % nTilesN) * FT_N;

    const int bc  = tid & 127;
    const int qr0 = tid >> 7;
    const float s  = scales[bcol + bc];
    const float nz = -zeros[bcol + bc];

    f32x4 acc[4][4];
    #pragma unroll
    for (int i = 0; i < 4; ++i)
        #pragma unroll
        for (int j = 0; j < 4; ++j)
            acc[i][j] = (f32x4){0.f, 0.f, 0.f, 0.f};

    for (int kt = 0; kt < K; kt += FT_K) {
        #pragma unroll
        for (int i = 0; i < 4; ++i) {
            int g  = tid + i * 256;
            int r  = g >> 3;
            int kbg = g & 7;
            const float* p = x + (size_t)(brow + r) * K + kt + kbg * 8;
            f32x4 f0 = *(const f32x4*)p;
            f32x4 f1 = *(const f32x4*)(p + 4);
            bf16x8 v;
            v[0] = (__bf16)f0[0]; v[1] = (__bf16)f0[1];
            v[2] = (__bf16)f0[2]; v[3] = (__bf16)f0[3];
            v[4] = (__bf16)f1[0]; v[5] = (__bf16)f1[1];
            v[6] = (__bf16)f1[2]; v[7] = (__bf16)f1[3];
            int slot = kbg ^ (r & 7);
            *(bf16x8*)&Alds[r * FT_K + slot * 8] = v;
        }
        #pragma unroll
        for (int i = 0; i < 4; ++i) {
            int qr = qr0 + i * 2;
            uint32_t wv = (uint32_t)qw[(size_t)(kt / 8 + qr) * N + bcol + bc];
            uint32_t lo = wv & 0x0F0F0F0Fu;
            uint32_t hi = (wv >> 4) & 0x0F0F0F0Fu;
            bf16x8 v;
            v[0] = (__bf16)fmaf(s, (float)(lo & 0xFFu),         nz);
            v[1] = (__bf16)fmaf(s, (float)(hi & 0xFFu),         nz);
            v[2] = (__bf16)fmaf(s, (float)((lo >> 8)  & 0xFFu), nz);
            v[3] = (__bf16)fmaf(s, (float)((hi >> 8)  & 0xFFu), nz);
            v[4] = (__bf16)fmaf(s, (float)((lo >> 16) & 0xFFu), nz);
            v[5] = (__bf16)fmaf(s, (float)((hi >> 16) & 0xFFu), nz);
            v[6] = (__bf16)fmaf(s, (float)(lo >> 24),           nz);
            v[7] = (__bf16)fmaf(s, (float)(hi >> 24),           nz);
            int slot = qr ^ (bc & 7);
            *(bf16x8*)&Blds[bc * FT_K + slot * 8] = v;
        }
        __syncthreads();

        #pragma unroll
        for (int ks = 0; ks < 2; ++ks) {
            const int slot = (ks * 4 + lkb) ^ (lrow & 7);
            const int abase = (wm * 64 + lrow) * FT_K + slot * 8;
            const int bbase = (wn * 64 + lrow) * FT_K + slot * 8;
            bf16x8 af[4], bfr[4];
            #pragma unroll
            for (int mf = 0; mf < 4; ++mf)
                af[mf] = *(const bf16x8*)&Alds[abase + mf * 16 * FT_K];
            #pragma unroll
            for (int nf = 0; nf < 4; ++nf)
                bfr[nf] = *(const bf16x8*)&Blds[bbase + nf * 16 * FT_K];
            #pragma unroll
            for (int mf = 0; mf < 4; ++mf)
                #pragma unroll
                for (int nf = 0; nf < 4; ++nf)
                    acc[mf][nf] = __builtin_amdgcn_mfma_f32_16x16x32_bf16(
                        af[mf], bfr[nf], acc[mf][nf], 0, 0, 0);
        }
        __syncthreads();
    }

    #pragma unroll
    for (int nf = 0; nf < 4; ++nf) {
        int col = bcol + wn * 64 + nf * 16 + lrow;
        float bv = bias[col];
        #pragma unroll
        for (int mf = 0; mf < 4; ++mf) {
            int row = brow + wm * 64 + mf * 16 + lkb * 4;
            #pragma unroll
            for (int i = 0; i < 4; ++i)
                out[(size_t)(row + i) * N + col] = acc[mf][nf][i] + bv;
        }
    }
}

extern "C" void kernel_launch(void* const* d_in, const int* in_sizes, int n_in,
                              void* d_out, int out_size, void* d_ws, size_t ws_size,
                              hipStream_t stream) {
    const float* x      = (const float*)d_in[0];
    const int*   qw     = (const int*)d_in[1];
    const float* scales = (const float*)d_in[2];
    const float* zeros  = (const float*)d_in[3];
    const float* bias   = (const float*)d_in[4];
    float* out = (float*)d_out;

    const int N = in_sizes[4];                              // OUT
    const int K = (int)(((long long)in_sizes[1] * 8) / N);  // IN
    const int M = in_sizes[0] / K;

    const size_t xb_elems = (size_t)M * K;
    const size_t wt_elems = (size_t)N * K;
    const size_t need = (xb_elems + wt_elems) * sizeof(__bf16);

    const bool shapes_ok = (M % BM == 0) && (N % BN == 0) && (K % 256 == 0) &&
                           (K / BK >= 4);

    if (ws_size >= need && shapes_ok) {
        __bf16* xb = (__bf16*)d_ws;
        __bf16* Wt = xb + xb_elems;

        size_t n8 = xb_elems / 8;
        cvt_x_kernel<<<dim3((unsigned)((n8 + 255) / 256)), 256, 0, stream>>>(x, xb, n8);

        dim3 dq_grid((unsigned)(((K / 8) / 32) * (N / 64)));
        dequant_w_kernel<<<dq_grid, 256, 0, stream>>>(qw, scales, zeros, Wt, N, K);

        dim3 grid((M / BM) * (N / BN));
        qgemm8_kernel<<<grid, 512, 0, stream>>>(xb, Wt, bias, out, M, N, K);
    } else {
        dim3 grid((M / FT_M) * (N / FT_N));
        qgemm_fused_kernel<<<grid, 256, 0, stream>>>(x, qw, scales, zeros, bias, out, M, N, K);
    }
}

// Round 7
// 300.603 us; speedup vs baseline: 1.6582x; 1.0659x over previous
//
#include <hip/hip_runtime.h>
#include <hip/hip_bf16.h>
#include <stdint.h>

// OldQuantLinear: y = x @ (scales.T * unpack4(qweight) - zeros.T) + bias
// R7: R6 (pre-dequant + 256x256 BK=32 4-deep-ring bf16 GEMM, swizzled LDS)
// with the sync structure relaxed to ONE barrier per K-tile:
//   [sched_barrier0] dsread p1 (8 b128) | STAGE_A(t+3) | prio1 MFMA*16 prio0 |
//   dsread p2 (4 b128) | STAGE_B(t+3) | prio1 MFMA*16 prio0 |
//   vmcnt(counted) [sched_barrier0] s_barrier
// Hazard ledger: (1) tile t+1 readiness = own-loads vmcnt + barrier (cross-wave);
// (2) STAGE(t+3) overwrites buf(t-1) — all t-1 ds_reads are consumed by MFMAs
// before the end-of-(t-1) barrier, and sched_barrier(0) pins motion inside the
// tile (rule 18: "memory" clobber does not order register-only MFMA/loads).
// Compiler manages read->MFMA lgkmcnt (no asm lgkm waits).

#define BM 256
#define BN 256
#define BK 32
#define NBUF 4

using f32x4  = __attribute__((ext_vector_type(4))) float;
using bf16x8 = __attribute__((ext_vector_type(8))) __bf16;

typedef const uint32_t __attribute__((address_space(1)))* gas_ptr;
typedef uint32_t __attribute__((address_space(3)))* las_ptr;

__device__ __forceinline__ void gl16(const __bf16* g, __bf16* l) {
    __builtin_amdgcn_global_load_lds((gas_ptr)g, (las_ptr)l, 16, 0, 0);
}

// ---------------- pre-pass 1: x f32 -> bf16 ----------------
__global__ __launch_bounds__(256) void cvt_x_kernel(
    const float* __restrict__ x, __bf16* __restrict__ xb, size_t n8)
{
    size_t i = (size_t)blockIdx.x * 256 + threadIdx.x;
    if (i >= n8) return;
    const f32x4* p = (const f32x4*)(x + i * 8);
    f32x4 a = p[0], b = p[1];
    bf16x8 v;
    v[0] = (__bf16)a[0]; v[1] = (__bf16)a[1]; v[2] = (__bf16)a[2]; v[3] = (__bf16)a[3];
    v[4] = (__bf16)b[0]; v[5] = (__bf16)b[1]; v[6] = (__bf16)b[2]; v[7] = (__bf16)b[3];
    *(bf16x8*)(xb + i * 8) = v;
}

// ---------------- pre-pass 2: qweight -> Wt [N][K] bf16 ----------------
__global__ __launch_bounds__(256) void dequant_w_kernel(
    const int* __restrict__ qw, const float* __restrict__ scales,
    const float* __restrict__ zeros, __bf16* __restrict__ Wt, int N, int K)
{
    __shared__ __align__(16) __bf16 T[64 * 32 * 8];
    const int tid = threadIdx.x;
    const int nTilesN = N >> 6;
    const int kg0 = (blockIdx.x / nTilesN) << 5;
    const int n0  = (blockIdx.x % nTilesN) << 6;

    #pragma unroll
    for (int it = 0; it < 8; ++it) {
        int idx  = it * 256 + tid;
        int kg_l = idx >> 6, n_l = idx & 63;
        int n = n0 + n_l;
        float s = scales[n], nz = -zeros[n];
        uint32_t w  = (uint32_t)qw[(size_t)(kg0 + kg_l) * N + n];
        uint32_t lo = w & 0x0F0F0F0Fu;
        uint32_t hi = (w >> 4) & 0x0F0F0F0Fu;
        bf16x8 v;
        v[0] = (__bf16)fmaf(s, (float)(lo & 0xFFu),         nz);
        v[1] = (__bf16)fmaf(s, (float)(hi & 0xFFu),         nz);
        v[2] = (__bf16)fmaf(s, (float)((lo >> 8)  & 0xFFu), nz);
        v[3] = (__bf16)fmaf(s, (float)((hi >> 8)  & 0xFFu), nz);
        v[4] = (__bf16)fmaf(s, (float)((lo >> 16) & 0xFFu), nz);
        v[5] = (__bf16)fmaf(s, (float)((hi >> 16) & 0xFFu), nz);
        v[6] = (__bf16)fmaf(s, (float)(lo >> 24),           nz);
        v[7] = (__bf16)fmaf(s, (float)(hi >> 24),           nz);
        int slot = kg_l ^ (n_l & 7);
        *(bf16x8*)&T[(size_t)(n_l * 32 + slot) * 8] = v;
    }
    __syncthreads();
    #pragma unroll
    for (int it = 0; it < 8; ++it) {
        int idx  = it * 256 + tid;
        int n_l  = idx >> 5, kg_l = idx & 31;
        bf16x8 v = *(const bf16x8*)&T[(size_t)(n_l * 32 + (kg_l ^ (n_l & 7))) * 8];
        *(bf16x8*)&Wt[(size_t)(n0 + n_l) * K + (size_t)(kg0 + kg_l) * 8] = v;
    }
}

// ---------------- main GEMM: 256x256, 8 waves, 4-ring, 1 barrier/tile ----
__global__ __launch_bounds__(512) void qgemm8_kernel(
    const __bf16* __restrict__ A, const __bf16* __restrict__ Bt,
    const float* __restrict__ bias, float* __restrict__ out,
    int M, int N, int K)
{
    __shared__ __align__(16) __bf16 Alds[NBUF * BM * BK];  // 64 KiB
    __shared__ __align__(16) __bf16 Blds[NBUF * BN * BK];  // 64 KiB

    const int tid = threadIdx.x;
    const int l   = tid & 63;
    const int w   = tid >> 6;
    const int wm  = w >> 2;        // 0..1 (M half, 128 rows)
    const int wn  = w & 3;         // 0..3 (N quarter, 64 cols)
    const int lr  = l & 15;
    const int lg  = l >> 4;        // 0..3

    // T1: bijective XCD swizzle (nwg % 8 == 0 for our shapes)
    int bid = (int)blockIdx.x;
    const int nwg = (int)gridDim.x;
    if ((nwg & 7) == 0) bid = (bid & 7) * (nwg >> 3) + (bid >> 3);

    const int nTilesN = N / BN;
    const int brow = (bid / nTilesN) * BM;
    const int bcol = (bid % nTilesN) * BN;

    // staging: gi = w*128 + j*64 + l ; row = w*32 + j*16 + (l>>2); slot = l&3
    // k-granule kb = (l&3) ^ ((l>>3)&3)   [source-swizzled, linear LDS dest]
    const int skb  = (l & 3) ^ ((l >> 3) & 3);
    const int srow = w * 32 + (l >> 2);
    const __bf16* aS0 = A  + (size_t)(brow + srow) * K + skb * 8;
    const __bf16* aS1 = aS0 + (size_t)16 * K;
    const __bf16* bS0 = Bt + (size_t)(bcol + srow) * K + skb * 8;
    const __bf16* bS1 = bS0 + (size_t)16 * K;
    __bf16* aD0 = &Alds[(w * 128) * 8];       // wave-uniform; HW adds lane*16B
    __bf16* aD1 = &Alds[(w * 128 + 64) * 8];
    __bf16* bD0 = &Blds[(w * 128) * 8];
    __bf16* bD1 = &Blds[(w * 128 + 64) * 8];

    #define STAGE_A(tt) { const size_t ko = (size_t)(tt) * BK;            \
        const int sb = ((tt) & 3) * (BM * BK);                            \
        gl16(aS0 + ko, aD0 + sb); gl16(aS1 + ko, aD1 + sb); }
    #define STAGE_B(tt) { const size_t ko = (size_t)(tt) * BK;            \
        const int sb = ((tt) & 3) * (BN * BK);                            \
        gl16(bS0 + ko, bD0 + sb); gl16(bS1 + ko, bD1 + sb); }

    f32x4 acc[8][4];
    #pragma unroll
    for (int i = 0; i < 8; ++i)
        #pragma unroll
        for (int j = 0; j < 4; ++j)
            acc[i][j] = (f32x4){0.f, 0.f, 0.f, 0.f};

    const int NT = K / BK;

    // read-side swizzled slot (mf/nf-invariant)
    const int rslot = lg ^ ((lr >> 1) & 3);

    // prologue: stage tiles 0,1,2; wait own tile-0 loads; join
    STAGE_A(0); STAGE_B(0);
    STAGE_A(1); STAGE_B(1);
    STAGE_A(2); STAGE_B(2);
    asm volatile("s_waitcnt vmcnt(8)" ::: "memory");
    __builtin_amdgcn_s_barrier();

    for (int t = 0; t < NT; ++t) {
        const int bo = (t & 3) * (BM * BK);
        const int abase = bo + (wm * 128 + lr) * BK + rslot * 8;
        const int bbase = bo + (wn * 64  + lr) * BK + rslot * 8;
        const bool pre = (t + 3 < NT);
        bf16x8 af[4], af2[4], bfr[4];

        __builtin_amdgcn_sched_barrier(0);   // nothing crosses the barrier from below

        // ---- half 1: m-frags 0-3 x n-frags 0-3 ----
        #pragma unroll
        for (int mf = 0; mf < 4; ++mf)
            af[mf] = *(const bf16x8*)&Alds[abase + mf * 16 * BK];
        #pragma unroll
        for (int nf = 0; nf < 4; ++nf)
            bfr[nf] = *(const bf16x8*)&Blds[bbase + nf * 16 * BK];
        if (pre) STAGE_A(t + 3);
        __builtin_amdgcn_s_setprio(1);
        #pragma unroll
        for (int mf = 0; mf < 4; ++mf)
            #pragma unroll
            for (int nf = 0; nf < 4; ++nf)
                acc[mf][nf] = __builtin_amdgcn_mfma_f32_16x16x32_bf16(
                    af[mf], bfr[nf], acc[mf][nf], 0, 0, 0);
        __builtin_amdgcn_s_setprio(0);

        // ---- half 2: m-frags 4-7 (reuse B frags) ----
        #pragma unroll
        for (int mf = 0; mf < 4; ++mf)
            af2[mf] = *(const bf16x8*)&Alds[abase + (mf + 4) * 16 * BK];
        if (pre) STAGE_B(t + 3);
        __builtin_amdgcn_s_setprio(1);
        #pragma unroll
        for (int mf = 0; mf < 4; ++mf)
            #pragma unroll
            for (int nf = 0; nf < 4; ++nf)
                acc[mf + 4][nf] = __builtin_amdgcn_mfma_f32_16x16x32_bf16(
                    af2[mf], bfr[nf], acc[mf + 4][nf], 0, 0, 0);
        __builtin_amdgcn_s_setprio(0);

        // counted vmcnt: retire exactly tile t+1's 4 loads
        if (pre)              { asm volatile("s_waitcnt vmcnt(8)" ::: "memory"); }
        else if (t + 2 < NT)  { asm volatile("s_waitcnt vmcnt(4)" ::: "memory"); }
        else                  { asm volatile("s_waitcnt vmcnt(0)" ::: "memory"); }
        __builtin_amdgcn_sched_barrier(0);   // nothing crosses from above
        __builtin_amdgcn_s_barrier();        // ONE barrier per K-tile
    }

    // ---- epilogue ----
    #pragma unroll
    for (int nf = 0; nf < 4; ++nf) {
        int col = bcol + wn * 64 + nf * 16 + lr;
        float bv = bias[col];
        #pragma unroll
        for (int mf = 0; mf < 8; ++mf) {
            int row = brow + wm * 128 + mf * 16 + lg * 4;
            #pragma unroll
            for (int i = 0; i < 4; ++i)
                out[(size_t)(row + i) * N + col] = acc[mf][nf][i] + bv;
        }
    }
    #undef STAGE_A
    #undef STAGE_B
}

// ---------------- fallback: fused kernel (R2) ----------------
#define FT_M 128
#define FT_N 128
#define FT_K 64
__global__ __launch_bounds__(256) void qgemm_fused_kernel(
    const float* __restrict__ x, const int* __restrict__ qw,
    const float* __restrict__ scales, const float* __restrict__ zeros,
    const float* __restrict__ bias, float* __restrict__ out,
    int M, int N, int K)
{
    __shared__ __align__(16) __bf16 Alds[FT_M * FT_K];
    __shared__ __align__(16) __bf16 Blds[FT_N * FT_K];

    const int tid  = threadIdx.x;
    const int lane = tid & 63;
    const int wave = tid >> 6;
    const int wm = wave >> 1, wn = wave & 1;
    const int lrow = lane & 15, lkb = lane >> 4;

    const int nTilesN = N / FT_N;
    const int brow = (blockIdx.x / nTilesN) * FT_M;
    const int bcol = (blockIdx.x % nTilesN) * FT_N;

    const int bc  = tid & 127;
    const int qr0 = tid >> 7;
    const float s  = scales[bcol + bc];
    const float nz = -zeros[bcol + bc];

    f32x4 acc[4][4];
    #pragma unroll
    for (int i = 0; i < 4; ++i)
        #pragma unroll
        for (int j = 0; j < 4; ++j)
            acc[i][j] = (f32x4){0.f, 0.f, 0.f, 0.f};

    for (int kt = 0; kt < K; kt += FT_K) {
        #pragma unroll
        for (int i = 0; i < 4; ++i) {
            int g  = tid + i * 256;
            int r  = g >> 3;
            int kbg = g & 7;
            const float* p = x + (size_t)(brow + r) * K + kt + kbg * 8;
            f32x4 f0 = *(const f32x4*)p;
            f32x4 f1 = *(const f32x4*)(p + 4);
            bf16x8 v;
            v[0] = (__bf16)f0[0]; v[1] = (__bf16)f0[1];
            v[2] = (__bf16)f0[2]; v[3] = (__bf16)f0[3];
            v[4] = (__bf16)f1[0]; v[5] = (__bf16)f1[1];
            v[6] = (__bf16)f1[2]; v[7] = (__bf16)f1[3];
            int slot = kbg ^ (r & 7);
            *(bf16x8*)&Alds[r * FT_K + slot * 8] = v;
        }
        #pragma unroll
        for (int i = 0; i < 4; ++i) {
            int qr = qr0 + i * 2;
            uint32_t wv = (uint32_t)qw[(size_t)(kt / 8 + qr) * N + bcol + bc];
            uint32_t lo = wv & 0x0F0F0F0Fu;
            uint32_t hi = (wv >> 4) & 0x0F0F0F0Fu;
            bf16x8 v;
            v[0] = (__bf16)fmaf(s, (float)(lo & 0xFFu),         nz);
            v[1] = (__bf16)fmaf(s, (float)(hi & 0xFFu),         nz);
            v[2] = (__bf16)fmaf(s, (float)((lo >> 8)  & 0xFFu), nz);
            v[3] = (__bf16)fmaf(s, (float)((hi >> 8)  & 0xFFu), nz);
            v[4] = (__bf16)fmaf(s, (float)((lo >> 16) & 0xFFu), nz);
            v[5] = (__bf16)fmaf(s, (float)((hi >> 16) & 0xFFu), nz);
            v[6] = (__bf16)fmaf(s, (float)(lo >> 24),           nz);
            v[7] = (__bf16)fmaf(s, (float)(hi >> 24),           nz);
            int slot = qr ^ (bc & 7);
            *(bf16x8*)&Blds[bc * FT_K + slot * 8] = v;
        }
        __syncthreads();

        #pragma unroll
        for (int ks = 0; ks < 2; ++ks) {
            const int slot = (ks * 4 + lkb) ^ (lrow & 7);
            const int abase = (wm * 64 + lrow) * FT_K + slot * 8;
            const int bbase = (wn * 64 + lrow) * FT_K + slot * 8;
            bf16x8 af[4], bfr[4];
            #pragma unroll
            for (int mf = 0; mf < 4; ++mf)
                af[mf] = *(const bf16x8*)&Alds[abase + mf * 16 * FT_K];
            #pragma unroll
            for (int nf = 0; nf < 4; ++nf)
                bfr[nf] = *(const bf16x8*)&Blds[bbase + nf * 16 * FT_K];
            #pragma unroll
            for (int mf = 0; mf < 4; ++mf)
                #pragma unroll
                for (int nf = 0; nf < 4; ++nf)
                    acc[mf][nf] = __builtin_amdgcn_mfma_f32_16x16x32_bf16(
                        af[mf], bfr[nf], acc[mf][nf], 0, 0, 0);
        }
        __syncthreads();
    }

    #pragma unroll
    for (int nf = 0; nf < 4; ++nf) {
        int col = bcol + wn * 64 + nf * 16 + lrow;
        float bv = bias[col];
        #pragma unroll
        for (int mf = 0; mf < 4; ++mf) {
            int row = brow + wm * 64 + mf * 16 + lkb * 4;
            #pragma unroll
            for (int i = 0; i < 4; ++i)
                out[(size_t)(row + i) * N + col] = acc[mf][nf][i] + bv;
        }
    }
}

extern "C" void kernel_launch(void* const* d_in, const int* in_sizes, int n_in,
                              void* d_out, int out_size, void* d_ws, size_t ws_size,
                              hipStream_t stream) {
    const float* x      = (const float*)d_in[0];
    const int*   qw     = (const int*)d_in[1];
    const float* scales = (const float*)d_in[2];
    const float* zeros  = (const float*)d_in[3];
    const float* bias   = (const float*)d_in[4];
    float* out = (float*)d_out;

    const int N = in_sizes[4];                              // OUT
    const int K = (int)(((long long)in_sizes[1] * 8) / N);  // IN
    const int M = in_sizes[0] / K;

    const size_t xb_elems = (size_t)M * K;
    const size_t wt_elems = (size_t)N * K;
    const size_t need = (xb_elems + wt_elems) * sizeof(__bf16);

    const bool shapes_ok = (M % BM == 0) && (N % BN == 0) && (K % 256 == 0) &&
                           (K / BK >= 4);

    if (ws_size >= need && shapes_ok) {
        __bf16* xb = (__bf16*)d_ws;
        __bf16* Wt = xb + xb_elems;

        size_t n8 = xb_elems / 8;
        cvt_x_kernel<<<dim3((unsigned)((n8 + 255) / 256)), 256, 0, stream>>>(x, xb, n8);

        dim3 dq_grid((unsigned)(((K / 8) / 32) * (N / 64)));
        dequant_w_kernel<<<dq_grid, 256, 0, stream>>>(qw, scales, zeros, Wt, N, K);

        dim3 grid((M / BM) * (N / BN));
        qgemm8_kernel<<<grid, 512, 0, stream>>>(xb, Wt, bias, out, M, N, K);
    } else {
        dim3 grid((M / FT_M) * (N / FT_N));
        qgemm_fused_kernel<<<grid, 256, 0, stream>>>(x, qw, scales, zeros, bias, out, M, N, K);
    }
}